// Round 2
// baseline (219.650 us; speedup 1.0000x reference)
//
#include <hip/hip_runtime.h>

typedef _Float16 half8 __attribute__((ext_vector_type(8)));
typedef _Float16 half4 __attribute__((ext_vector_type(4)));
typedef __fp16 f16x2 __attribute__((ext_vector_type(2)));
typedef __fp16 f16x4 __attribute__((ext_vector_type(4)));
typedef float floatx16 __attribute__((ext_vector_type(16)));

#define MFMA_F16(A, B, C) __builtin_amdgcn_mfma_f32_32x32x16_f16(A, B, C, 0, 0, 0)

constexpr int Bn = 4;     // batch
constexpr int Cc = 256;   // channels
constexpr int Cq = 32;    // C/8
constexpr int Nn = 4096;  // tokens (64*64)
constexpr float LOG2E = 1.44269504088896340736f;

// Layouts:
//   K4[b][cidx=0..3][n][8] : K fragment chunk cidx=(Cq>>3), dense across lanes
//   V8[b][nb=n>>3][c][8]   : V A-fragment, lane ml -> consecutive 16B chunks

__device__ inline floatx16 zero16() {
  floatx16 z;
#pragma unroll
  for (int i = 0; i < 16; ++i) z[i] = 0.f;
  return z;
}

// ---------------------------------------------------------------------------
// Kernel 0: W fp32 -> f16 (Wf scaled by log2e for exp2-domain softmax).
// ---------------------------------------------------------------------------
__global__ __launch_bounds__(256) void k_wconv(
    const float* __restrict__ Wf, const float* __restrict__ Wg,
    const float* __restrict__ Wh, _Float16* __restrict__ Wfh,
    _Float16* __restrict__ Wgh, _Float16* __restrict__ Whh) {
  int e = (blockIdx.x * 256 + threadIdx.x) * 4;
  const float* src;
  _Float16* dst;
  float sc = 1.f;
  if (e < 8192) { src = Wf + e; dst = Wfh + e; sc = LOG2E; }
  else if (e < 16384) { src = Wg + (e - 8192); dst = Wgh + (e - 8192); }
  else { src = Wh + (e - 16384); dst = Whh + (e - 16384); }
  float4 v = *(const float4*)src;
  half4 o;
  o[0] = (_Float16)(v.x * sc); o[1] = (_Float16)(v.y * sc);
  o[2] = (_Float16)(v.z * sc); o[3] = (_Float16)(v.w * sc);
  *(half4*)dst = o;
}

// ---------------------------------------------------------------------------
// Kernel 1: projections. Stage the 32-token x tile in LDS (transposed,
// coalesced float4 global reads) and build the 16 MFMA B-fragments ONCE per
// wave in registers -- they are identical for all 10 projection tiles.
// Store patterns unchanged from the proven round-9 kernel.
// ---------------------------------------------------------------------------
__global__ __launch_bounds__(256) void k_proj(
    const float* __restrict__ x,
    const _Float16* __restrict__ Wfh, const float* __restrict__ bf,
    const _Float16* __restrict__ Wgh, const float* __restrict__ bg,
    const _Float16* __restrict__ Whh, const float* __restrict__ bh,
    _Float16* __restrict__ Q, _Float16* __restrict__ K4,
    _Float16* __restrict__ V8) {
  __shared__ float xs[32][260];  // pad 260: 16B-aligned rows, ~4-way on read
  int tid = threadIdx.x;
  int w = tid >> 6, lane = tid & 63;
  int ml = lane & 31, h = lane >> 5;
  int b = blockIdx.x >> 7, nt = blockIdx.x & 127;
  int n0 = nt * 32;

  // ---- stage x[b][0..255][n0..n0+31] transposed into xs[n_local][c] ----
  {
    int c = tid >> 3;          // 0..31
    int nl = (tid & 7) * 4;    // 4 consecutive tokens per thread
    const float* xp = x + (size_t)b * Cc * Nn + n0 + nl;
#pragma unroll
    for (int pass = 0; pass < 8; ++pass) {
      int cc = c + pass * 32;
      float4 v = *(const float4*)(xp + (size_t)cc * Nn);
      xs[nl + 0][cc] = v.x;
      xs[nl + 1][cc] = v.y;
      xs[nl + 2][cc] = v.z;
      xs[nl + 3][cc] = v.w;
    }
  }
  __syncthreads();

  // ---- build all 16 B-fragments once (lane ml = token n0+ml) ----
  half8 bfr[16];
#pragma unroll
  for (int kc = 0; kc < 16; ++kc) {
    const float* xp = &xs[ml][kc * 16 + h * 8];
    half8 f;
#pragma unroll
    for (int j = 0; j < 8; ++j) f[j] = (_Float16)xp[j];  // RTE, matches r9
    bfr[kc] = f;
  }

  for (int t = w; t < 10; t += 4) {
    const _Float16* W;
    const float* bias;
    float bscale = 1.f;
    int o0 = 0;
    if (t == 0) { W = Wfh; bias = bf; bscale = LOG2E; }
    else if (t == 1) { W = Wgh; bias = bg; }
    else { W = Whh + (size_t)(t - 2) * 32 * Cc; bias = bh + (t - 2) * 32; o0 = (t - 2) * 32; }

    floatx16 acc = zero16();
    const _Float16* wp = W + (size_t)ml * Cc + h * 8;
#pragma unroll
    for (int kc = 0; kc < 16; ++kc) {
      half8 a = *(const half8*)(wp + kc * 16);
      acc = MFMA_F16(a, bfr[kc], acc);
    }

    if (t == 0) {
      // Q token-major Q[b][n][o]
      _Float16* op = Q + ((size_t)b * Nn + n0 + ml) * Cq;
#pragma unroll
      for (int qd = 0; qd < 4; ++qd) {
        float4 bq = *(const float4*)(bias + 8 * qd + 4 * h);
        const float* bqp = (const float*)&bq;
#pragma unroll
        for (int i = 0; i < 4; ++i) {
          int crow = i + 8 * qd + 4 * h;
          op[crow] = (_Float16)(acc[4 * qd + i] + bqp[i] * bscale);
        }
      }
    } else if (t == 1) {
      // K4[b][crow>>3][n][crow&7]
#pragma unroll
      for (int qd = 0; qd < 4; ++qd) {
        float4 bq = *(const float4*)(bias + 8 * qd + 4 * h);
        const float* bqp = (const float*)&bq;
#pragma unroll
        for (int i = 0; i < 4; ++i) {
          int crow = i + 8 * qd + 4 * h;
          K4[(((size_t)b * 4 + (crow >> 3)) * Nn + n0 + ml) * 8 + (crow & 7)] =
              (_Float16)(acc[4 * qd + i] + bqp[i]);
        }
      }
    } else {
      // V8[b][(n0+ml)>>3][c][ml&7]
      size_t nb = (size_t)((n0 + ml) >> 3);
      _Float16* op = V8 + (((size_t)b * 512 + nb) * 256) * 8 + (ml & 7);
#pragma unroll
      for (int qd = 0; qd < 4; ++qd) {
        float4 bq = *(const float4*)(bias + 8 * qd + 4 * h);
        const float* bqp = (const float*)&bq;
#pragma unroll
        for (int i = 0; i < 4; ++i) {
          int crow = i + 8 * qd + 4 * h;
          op[(size_t)(o0 + crow) * 8] = (_Float16)(acc[4 * qd + i] + bqp[i]);
        }
      }
    }
  }
}

// ---------------------------------------------------------------------------
// Kernel 2: pass-1 row max (log2-domain), K4 coalesced loads.
// MFMA bitwise identical to k_attn's S -> exp2(s-M) <= 1 exactly.
// ---------------------------------------------------------------------------
__global__ __launch_bounds__(512) void k_rowmax(const _Float16* __restrict__ Q,
                                                const _Float16* __restrict__ K4,
                                                float* __restrict__ M) {
  __shared__ float red[8][32];
  int tid = threadIdx.x, w = tid >> 6, lane = tid & 63;
  int ml = lane & 31, h = lane >> 5;
  int b = blockIdx.x >> 7, mt = blockIdx.x & 127;
  int m0 = mt * 32;
  const _Float16* qp = Q + ((size_t)b * Nn + m0 + ml) * Cq + h * 8;
  half8 qb0 = *(const half8*)(qp);
  half8 qb1 = *(const half8*)(qp + 16);
  const _Float16* kp0 = K4 + (((size_t)b * 4 + h) * Nn + w * 512 + ml) * 8;
  const _Float16* kp1 = K4 + (((size_t)b * 4 + 2 + h) * Nn + w * 512 + ml) * 8;
  float mx = -3.0e38f;
  for (int t = 0; t < 16; ++t) {
    floatx16 s = zero16();
    half8 k0 = *(const half8*)(kp0 + (size_t)t * 32 * 8);
    half8 k1 = *(const half8*)(kp1 + (size_t)t * 32 * 8);
    s = MFMA_F16(k0, qb0, s);
    s = MFMA_F16(k1, qb1, s);
#pragma unroll
    for (int i = 0; i < 16; ++i) mx = fmaxf(mx, s[i]);
  }
  mx = fmaxf(mx, __shfl_xor(mx, 32, 64));
  if (h == 0) red[w][ml] = mx;
  __syncthreads();
  if (tid < 32) {
    float m2 = red[0][tid];
#pragma unroll
    for (int i = 1; i < 8; ++i) m2 = fmaxf(m2, red[i][tid]);
    M[(size_t)b * Nn + m0 + tid] = m2;
  }
}

// ---------------------------------------------------------------------------
// Kernel 3: pass-2 attention. Changes this round:
//  * raw v_exp_f32 (__builtin_amdgcn_exp2f) -- arg <= 0, no fixup needed
//  * v_cvt_pkrtz packing for P -> f16 (bit-cast __fp16x4 -> half4)
//  * __launch_bounds__(512,8) + NC=4 chunks -> 4 blocks/CU (LDS 4x33KB fits)
// Structure otherwise identical to proven round-9 kernel.
// ---------------------------------------------------------------------------
__global__ __launch_bounds__(512, 8) void k_attn(
    const _Float16* __restrict__ Q, const _Float16* __restrict__ K4,
    const _Float16* __restrict__ V8, const float* __restrict__ M,
    _Float16* __restrict__ Opart, float* __restrict__ lpart, int nspan) {
  __shared__ _Float16 P[2 * 64 * 128];
  __shared__ float lred[8][32];
  int tid = threadIdx.x, w = tid >> 6, lane = tid & 63;
  int ml = lane & 31, h = lane >> 5;
  int msub = w & 1, nq = w >> 1;
  int bx = blockIdx.x;
  int mt = bx & 63, b = (bx >> 6) & 3, nc = bx >> 8;
  int m0 = mt * 64;
  int nbase0 = nc * nspan;
  int sw = ml & 15;

  const _Float16* qp = Q + ((size_t)b * Nn + m0 + msub * 32 + ml) * Cq + h * 8;
  half8 qb0 = *(const half8*)(qp);
  half8 qb1 = *(const half8*)(qp + 16);
  float Mv = M[(size_t)b * Nn + m0 + msub * 32 + ml];
  float lacc = 0.f;

  // K4 fragments: n = nbase0 + it*128 + nq*32 + ml  (coalesced across ml)
  const _Float16* k4b0 =
      K4 + (((size_t)b * 4 + h) * Nn + nbase0 + nq * 32 + ml) * 8;
  const _Float16* k4b1 =
      K4 + (((size_t)b * 4 + 2 + h) * Nn + nbase0 + nq * 32 + ml) * 8;

  int c0 = w * 32;
  // V8: nb = (nbase0>>3) + it*16 + kc*2 + h; elem ((b*512+nb)*256 + c)*8
  const _Float16* v8b =
      V8 + (((size_t)b * 512 + (nbase0 >> 3)) * 256 + c0 + ml) * 8;

  floatx16 o0 = zero16(), o1 = zero16();
  int iters = nspan >> 7;
  _Float16* pwbase = &P[(msub * 32 + ml) * 128];
  const _Float16* pr0 = &P[ml * 128];
  const _Float16* pr1 = &P[(32 + ml) * 128];

  for (int it = 0; it < iters; ++it) {
    int bufo = (it & 1) * (64 * 128);
    // ---- S phase ----
    {
      floatx16 s = zero16();
      half8 k0 = *(const half8*)(k4b0 + (size_t)it * 128 * 8);
      half8 k1 = *(const half8*)(k4b1 + (size_t)it * 128 * 8);
      s = MFMA_F16(k0, qb0, s);
      s = MFMA_F16(k1, qb1, s);
      _Float16* pw = pwbase + bufo;
#pragma unroll
      for (int q = 0; q < 4; ++q) {
        float p0 = __builtin_amdgcn_exp2f(s[4 * q + 0] - Mv);
        float p1 = __builtin_amdgcn_exp2f(s[4 * q + 1] - Mv);
        float p2 = __builtin_amdgcn_exp2f(s[4 * q + 2] - Mv);
        float p3 = __builtin_amdgcn_exp2f(s[4 * q + 3] - Mv);
        lacc += (p0 + p1) + (p2 + p3);
        f16x4 pkv = __builtin_shufflevector(__builtin_amdgcn_cvt_pkrtz(p0, p1),
                                            __builtin_amdgcn_cvt_pkrtz(p2, p3),
                                            0, 1, 2, 3);
        half4 pk = __builtin_bit_cast(half4, pkv);
        *(half4*)(pw + ((nq * 4 + q) ^ sw) * 8 + 4 * h) = pk;  // ds_write_b64
      }
    }
    __syncthreads();
    // ---- PV phase: coalesced V + swizzled P reads ----
    {
      const _Float16* vp = v8b + (size_t)it * 16 * 2048;  // 2048 = 256*8
      const _Float16* p0b = pr0 + bufo;
      const _Float16* p1b = pr1 + bufo;
#pragma unroll
      for (int kc = 0; kc < 8; ++kc) {
        half8 vf = *(const half8*)(vp + (size_t)(kc * 2 + h) * 2048);
        int chunk = (kc * 2 + h) ^ sw;
        half8 pb0 = *(const half8*)(p0b + chunk * 8);  // ds_read_b128
        half8 pb1 = *(const half8*)(p1b + chunk * 8);
        o0 = MFMA_F16(vf, pb0, o0);
        o1 = MFMA_F16(vf, pb1, o1);
      }
    }
  }

  // ---- l reduction: wave w holds partial l for msub=w&1, n-stripe nq ----
  lacc += __shfl_xor(lacc, 32, 64);
  if (h == 0) lred[w][ml] = lacc;
  __syncthreads();
  if (w < 2 && h == 0) {
    float lsum = lred[w][ml] + lred[w + 2][ml] + lred[w + 4][ml] + lred[w + 6][ml];
    lpart[((size_t)nc * Bn + b) * Nn + m0 + w * 32 + ml] = lsum;
  }

  // ---- store unnormalized O^T partials (f16) ----
  _Float16* op0 = Opart + ((size_t)((size_t)nc * Bn + b) * Cc) * Nn + (m0 + ml);
#pragma unroll
  for (int r = 0; r < 16; ++r) {
    int c = c0 + (r & 3) + 8 * (r >> 2) + 4 * h;
    op0[(size_t)c * Nn] = (_Float16)o0[r];
    op0[(size_t)c * Nn + 32] = (_Float16)o1[r];
  }
}

// ---------------------------------------------------------------------------
// Kernel 4: combine chunk partials: out = gamma*(sum O)/(sum l) + input
// ---------------------------------------------------------------------------
__global__ __launch_bounds__(256) void k_fin(const _Float16* __restrict__ Op,
                                             const float* __restrict__ lp,
                                             const float* __restrict__ inp,
                                             const float* __restrict__ gamma,
                                             float* __restrict__ out, int NC) {
  int i4 = (blockIdx.x * 256 + threadIdx.x) * 4;
  int m = i4 & (Nn - 1);
  int bc = i4 >> 12;        // b*256 + c
  int b = bc >> 8;
  float ax = 0.f, ay = 0.f, az = 0.f, aw = 0.f;
  float lx = 0.f, ly = 0.f, lz = 0.f, lw = 0.f;
  for (int nc = 0; nc < NC; ++nc) {
    half4 o = *(const half4*)(Op + ((size_t)nc * Bn * Cc + bc) * Nn + m);
    float4 lv = *(const float4*)(lp + ((size_t)nc * Bn + b) * Nn + m);
    ax += (float)o[0]; ay += (float)o[1]; az += (float)o[2]; aw += (float)o[3];
    lx += lv.x; ly += lv.y; lz += lv.z; lw += lv.w;
  }
  float g = gamma[0];
  float4 xi = *(const float4*)(inp + (size_t)i4);
  float4 r;
  r.x = g * ax / lx + xi.x;
  r.y = g * ay / ly + xi.y;
  r.z = g * az / lz + xi.z;
  r.w = g * aw / lw + xi.w;
  *(float4*)(out + (size_t)i4) = r;
}

// ---------------------------------------------------------------------------
extern "C" void kernel_launch(void* const* d_in, const int* in_sizes, int n_in,
                              void* d_out, int out_size, void* d_ws,
                              size_t ws_size, hipStream_t stream) {
  const float* x = (const float*)d_in[0];
  const float* Wf = (const float*)d_in[1];
  const float* bf = (const float*)d_in[2];
  const float* Wg = (const float*)d_in[3];
  const float* bg = (const float*)d_in[4];
  const float* Wh = (const float*)d_in[5];
  const float* bh = (const float*)d_in[6];
  const float* gamma = (const float*)d_in[7];
  float* out = (float*)d_out;

  char* ws = (char*)d_ws;
  // Layout (bytes):
  //   Q      [0,        1048576)
  //   K4     [1048576,  2097152)
  //   V8     [2097152, 10485760)
  //   M      [10485760, 10551296)
  //   Wfh    [10551296, 10567680)
  //   Wgh    [10567680, 10584064)
  //   Whh    [10584064, 10715136)
  //   lpart  [10715136, 10715136 + NC*65536)
  //   Opart  [.., + NC*8388608)
  _Float16* Q  = (_Float16*)(ws);
  _Float16* K4 = (_Float16*)(ws + 1048576);
  _Float16* V8 = (_Float16*)(ws + 2097152);
  float*    M  = (float*)   (ws + 10485760);
  _Float16* Wfh = (_Float16*)(ws + 10551296);
  _Float16* Wgh = (_Float16*)(ws + 10567680);
  _Float16* Whh = (_Float16*)(ws + 10584064);

  size_t base = 10715136u;
  size_t per_chunk = 65536u + 8388608u;
  int NC = 1;
  if (ws_size >= base + 4u * per_chunk) NC = 4;
  else if (ws_size >= base + 2u * per_chunk) NC = 2;
  int nspan = Nn / NC;

  float*    lpart = (float*)(ws + base);
  _Float16* Opart = (_Float16*)(ws + base + (size_t)NC * 65536u);

  k_wconv<<<dim3(80), dim3(256), 0, stream>>>(Wf, Wg, Wh, Wfh, Wgh, Whh);
  k_proj<<<dim3(512), dim3(256), 0, stream>>>(x, Wfh, bf, Wgh, bg, Whh, bh, Q, K4, V8);
  k_rowmax<<<dim3(512), dim3(512), 0, stream>>>(Q, K4, M);
  k_attn<<<dim3(NC * 256), dim3(512), 0, stream>>>(Q, K4, V8, M, Opart, lpart, nspan);
  k_fin<<<dim3(4096), dim3(256), 0, stream>>>(Opart, lpart, x, gamma, out, NC);
}

// Round 3
// 165.445 us; speedup vs baseline: 1.3276x; 1.3276x over previous
//
#include <hip/hip_runtime.h>

typedef _Float16 half8 __attribute__((ext_vector_type(8)));
typedef _Float16 half4 __attribute__((ext_vector_type(4)));
typedef __fp16 f16x2 __attribute__((ext_vector_type(2)));
typedef __fp16 f16x4 __attribute__((ext_vector_type(4)));
typedef float floatx16 __attribute__((ext_vector_type(16)));

#define MFMA_F16(A, B, C) __builtin_amdgcn_mfma_f32_32x32x16_f16(A, B, C, 0, 0, 0)

constexpr int Bn = 4;     // batch
constexpr int Cc = 256;   // channels
constexpr int Cq = 32;    // C/8
constexpr int Nn = 4096;  // tokens (64*64)
constexpr float LOG2E = 1.44269504088896340736f;

// Layouts:
//   K4[b][cidx=0..3][n][8] : K fragment chunk cidx=(Cq>>3), dense across lanes
//   V8[b][nb=n>>3][c][8]   : V A-fragment, lane ml -> consecutive 16B chunks

__device__ inline floatx16 zero16() {
  floatx16 z;
#pragma unroll
  for (int i = 0; i < 16; ++i) z[i] = 0.f;
  return z;
}

// ---------------------------------------------------------------------------
// Kernel 0: W fp32 -> f16 (Wf scaled by log2e for exp2-domain softmax).
// ---------------------------------------------------------------------------
__global__ __launch_bounds__(256) void k_wconv(
    const float* __restrict__ Wf, const float* __restrict__ Wg,
    const float* __restrict__ Wh, _Float16* __restrict__ Wfh,
    _Float16* __restrict__ Wgh, _Float16* __restrict__ Whh) {
  int e = (blockIdx.x * 256 + threadIdx.x) * 4;
  const float* src;
  _Float16* dst;
  float sc = 1.f;
  if (e < 8192) { src = Wf + e; dst = Wfh + e; sc = LOG2E; }
  else if (e < 16384) { src = Wg + (e - 8192); dst = Wgh + (e - 8192); }
  else { src = Wh + (e - 16384); dst = Whh + (e - 16384); }
  float4 v = *(const float4*)src;
  half4 o;
  o[0] = (_Float16)(v.x * sc); o[1] = (_Float16)(v.y * sc);
  o[2] = (_Float16)(v.z * sc); o[3] = (_Float16)(v.w * sc);
  *(half4*)dst = o;
}

// ---------------------------------------------------------------------------
// Kernel 1: projections. Stage the 32-token x tile in LDS (transposed,
// coalesced float4 global reads) and build the 16 MFMA B-fragments ONCE per
// wave in registers -- they are identical for all 10 projection tiles.
// Store patterns unchanged from the proven round-9 kernel.
// ---------------------------------------------------------------------------
__global__ __launch_bounds__(256) void k_proj(
    const float* __restrict__ x,
    const _Float16* __restrict__ Wfh, const float* __restrict__ bf,
    const _Float16* __restrict__ Wgh, const float* __restrict__ bg,
    const _Float16* __restrict__ Whh, const float* __restrict__ bh,
    _Float16* __restrict__ Q, _Float16* __restrict__ K4,
    _Float16* __restrict__ V8) {
  __shared__ float xs[32][260];  // pad 260: 16B-aligned rows, ~4-way on read
  int tid = threadIdx.x;
  int w = tid >> 6, lane = tid & 63;
  int ml = lane & 31, h = lane >> 5;
  int b = blockIdx.x >> 7, nt = blockIdx.x & 127;
  int n0 = nt * 32;

  // ---- stage x[b][0..255][n0..n0+31] transposed into xs[n_local][c] ----
  {
    int c = tid >> 3;          // 0..31
    int nl = (tid & 7) * 4;    // 4 consecutive tokens per thread
    const float* xp = x + (size_t)b * Cc * Nn + n0 + nl;
#pragma unroll
    for (int pass = 0; pass < 8; ++pass) {
      int cc = c + pass * 32;
      float4 v = *(const float4*)(xp + (size_t)cc * Nn);
      xs[nl + 0][cc] = v.x;
      xs[nl + 1][cc] = v.y;
      xs[nl + 2][cc] = v.z;
      xs[nl + 3][cc] = v.w;
    }
  }
  __syncthreads();

  // ---- build all 16 B-fragments once (lane ml = token n0+ml) ----
  half8 bfr[16];
#pragma unroll
  for (int kc = 0; kc < 16; ++kc) {
    const float* xp = &xs[ml][kc * 16 + h * 8];
    half8 f;
#pragma unroll
    for (int j = 0; j < 8; ++j) f[j] = (_Float16)xp[j];  // RTE, matches r9
    bfr[kc] = f;
  }

  for (int t = w; t < 10; t += 4) {
    const _Float16* W;
    const float* bias;
    float bscale = 1.f;
    int o0 = 0;
    if (t == 0) { W = Wfh; bias = bf; bscale = LOG2E; }
    else if (t == 1) { W = Wgh; bias = bg; }
    else { W = Whh + (size_t)(t - 2) * 32 * Cc; bias = bh + (t - 2) * 32; o0 = (t - 2) * 32; }

    floatx16 acc = zero16();
    const _Float16* wp = W + (size_t)ml * Cc + h * 8;
#pragma unroll
    for (int kc = 0; kc < 16; ++kc) {
      half8 a = *(const half8*)(wp + kc * 16);
      acc = MFMA_F16(a, bfr[kc], acc);
    }

    if (t == 0) {
      // Q token-major Q[b][n][o]
      _Float16* op = Q + ((size_t)b * Nn + n0 + ml) * Cq;
#pragma unroll
      for (int qd = 0; qd < 4; ++qd) {
        float4 bq = *(const float4*)(bias + 8 * qd + 4 * h);
        const float* bqp = (const float*)&bq;
#pragma unroll
        for (int i = 0; i < 4; ++i) {
          int crow = i + 8 * qd + 4 * h;
          op[crow] = (_Float16)(acc[4 * qd + i] + bqp[i] * bscale);
        }
      }
    } else if (t == 1) {
      // K4[b][crow>>3][n][crow&7]
#pragma unroll
      for (int qd = 0; qd < 4; ++qd) {
        float4 bq = *(const float4*)(bias + 8 * qd + 4 * h);
        const float* bqp = (const float*)&bq;
#pragma unroll
        for (int i = 0; i < 4; ++i) {
          int crow = i + 8 * qd + 4 * h;
          K4[(((size_t)b * 4 + (crow >> 3)) * Nn + n0 + ml) * 8 + (crow & 7)] =
              (_Float16)(acc[4 * qd + i] + bqp[i]);
        }
      }
    } else {
      // V8[b][(n0+ml)>>3][c][ml&7]
      size_t nb = (size_t)((n0 + ml) >> 3);
      _Float16* op = V8 + (((size_t)b * 512 + nb) * 256) * 8 + (ml & 7);
#pragma unroll
      for (int qd = 0; qd < 4; ++qd) {
        float4 bq = *(const float4*)(bias + 8 * qd + 4 * h);
        const float* bqp = (const float*)&bq;
#pragma unroll
        for (int i = 0; i < 4; ++i) {
          int crow = i + 8 * qd + 4 * h;
          op[(size_t)(o0 + crow) * 8] = (_Float16)(acc[4 * qd + i] + bqp[i]);
        }
      }
    }
  }
}

// ---------------------------------------------------------------------------
// Kernel 2: pass-1 row max (log2-domain), K4 coalesced loads.
// MFMA bitwise identical to k_attn's S -> exp2(s-M) <= 1 exactly.
// ---------------------------------------------------------------------------
__global__ __launch_bounds__(512) void k_rowmax(const _Float16* __restrict__ Q,
                                                const _Float16* __restrict__ K4,
                                                float* __restrict__ M) {
  __shared__ float red[8][32];
  int tid = threadIdx.x, w = tid >> 6, lane = tid & 63;
  int ml = lane & 31, h = lane >> 5;
  int b = blockIdx.x >> 7, mt = blockIdx.x & 127;
  int m0 = mt * 32;
  const _Float16* qp = Q + ((size_t)b * Nn + m0 + ml) * Cq + h * 8;
  half8 qb0 = *(const half8*)(qp);
  half8 qb1 = *(const half8*)(qp + 16);
  const _Float16* kp0 = K4 + (((size_t)b * 4 + h) * Nn + w * 512 + ml) * 8;
  const _Float16* kp1 = K4 + (((size_t)b * 4 + 2 + h) * Nn + w * 512 + ml) * 8;
  float mx = -3.0e38f;
  for (int t = 0; t < 16; ++t) {
    floatx16 s = zero16();
    half8 k0 = *(const half8*)(kp0 + (size_t)t * 32 * 8);
    half8 k1 = *(const half8*)(kp1 + (size_t)t * 32 * 8);
    s = MFMA_F16(k0, qb0, s);
    s = MFMA_F16(k1, qb1, s);
#pragma unroll
    for (int i = 0; i < 16; ++i) mx = fmaxf(mx, s[i]);
  }
  mx = fmaxf(mx, __shfl_xor(mx, 32, 64));
  if (h == 0) red[w][ml] = mx;
  __syncthreads();
  if (tid < 32) {
    float m2 = red[0][tid];
#pragma unroll
    for (int i = 1; i < 8; ++i) m2 = fmaxf(m2, red[i][tid]);
    M[(size_t)b * Nn + m0 + tid] = m2;
  }
}

// ---------------------------------------------------------------------------
// Kernel 3: pass-2 attention. Round-3 config:
//  * NC=2 + __launch_bounds__(512,4): the PROVEN memory/occupancy shape
//    (round-2's NC=4 + (512,8) thrashed L2: FETCH 37->227MB, VGPR 52->32)
//  * raw v_exp_f32 (__builtin_amdgcn_exp2f) -- arg <= 0, no fixup needed
//  * v_cvt_pkrtz packing for P -> f16 (bit-cast __fp16x4 -> half4)
// ---------------------------------------------------------------------------
__global__ __launch_bounds__(512, 4) void k_attn(
    const _Float16* __restrict__ Q, const _Float16* __restrict__ K4,
    const _Float16* __restrict__ V8, const float* __restrict__ M,
    _Float16* __restrict__ Opart, float* __restrict__ lpart, int nspan) {
  __shared__ _Float16 P[2 * 64 * 128];
  __shared__ float lred[8][32];
  int tid = threadIdx.x, w = tid >> 6, lane = tid & 63;
  int ml = lane & 31, h = lane >> 5;
  int msub = w & 1, nq = w >> 1;
  int bx = blockIdx.x;
  int mt = bx & 63, b = (bx >> 6) & 3, nc = bx >> 8;
  int m0 = mt * 64;
  int nbase0 = nc * nspan;
  int sw = ml & 15;

  const _Float16* qp = Q + ((size_t)b * Nn + m0 + msub * 32 + ml) * Cq + h * 8;
  half8 qb0 = *(const half8*)(qp);
  half8 qb1 = *(const half8*)(qp + 16);
  float Mv = M[(size_t)b * Nn + m0 + msub * 32 + ml];
  float lacc = 0.f;

  // K4 fragments: n = nbase0 + it*128 + nq*32 + ml  (coalesced across ml)
  const _Float16* k4b0 =
      K4 + (((size_t)b * 4 + h) * Nn + nbase0 + nq * 32 + ml) * 8;
  const _Float16* k4b1 =
      K4 + (((size_t)b * 4 + 2 + h) * Nn + nbase0 + nq * 32 + ml) * 8;

  int c0 = w * 32;
  // V8: nb = (nbase0>>3) + it*16 + kc*2 + h; elem ((b*512+nb)*256 + c)*8
  const _Float16* v8b =
      V8 + (((size_t)b * 512 + (nbase0 >> 3)) * 256 + c0 + ml) * 8;

  floatx16 o0 = zero16(), o1 = zero16();
  int iters = nspan >> 7;
  _Float16* pwbase = &P[(msub * 32 + ml) * 128];
  const _Float16* pr0 = &P[ml * 128];
  const _Float16* pr1 = &P[(32 + ml) * 128];

  for (int it = 0; it < iters; ++it) {
    int bufo = (it & 1) * (64 * 128);
    // ---- S phase ----
    {
      floatx16 s = zero16();
      half8 k0 = *(const half8*)(k4b0 + (size_t)it * 128 * 8);
      half8 k1 = *(const half8*)(k4b1 + (size_t)it * 128 * 8);
      s = MFMA_F16(k0, qb0, s);
      s = MFMA_F16(k1, qb1, s);
      _Float16* pw = pwbase + bufo;
#pragma unroll
      for (int q = 0; q < 4; ++q) {
        float p0 = __builtin_amdgcn_exp2f(s[4 * q + 0] - Mv);
        float p1 = __builtin_amdgcn_exp2f(s[4 * q + 1] - Mv);
        float p2 = __builtin_amdgcn_exp2f(s[4 * q + 2] - Mv);
        float p3 = __builtin_amdgcn_exp2f(s[4 * q + 3] - Mv);
        lacc += (p0 + p1) + (p2 + p3);
        f16x4 pkv = __builtin_shufflevector(__builtin_amdgcn_cvt_pkrtz(p0, p1),
                                            __builtin_amdgcn_cvt_pkrtz(p2, p3),
                                            0, 1, 2, 3);
        half4 pk = __builtin_bit_cast(half4, pkv);
        *(half4*)(pw + ((nq * 4 + q) ^ sw) * 8 + 4 * h) = pk;  // ds_write_b64
      }
    }
    __syncthreads();
    // ---- PV phase: coalesced V + swizzled P reads ----
    {
      const _Float16* vp = v8b + (size_t)it * 16 * 2048;  // 2048 = 256*8
      const _Float16* p0b = pr0 + bufo;
      const _Float16* p1b = pr1 + bufo;
#pragma unroll
      for (int kc = 0; kc < 8; ++kc) {
        half8 vf = *(const half8*)(vp + (size_t)(kc * 2 + h) * 2048);
        int chunk = (kc * 2 + h) ^ sw;
        half8 pb0 = *(const half8*)(p0b + chunk * 8);  // ds_read_b128
        half8 pb1 = *(const half8*)(p1b + chunk * 8);
        o0 = MFMA_F16(vf, pb0, o0);
        o1 = MFMA_F16(vf, pb1, o1);
      }
    }
  }

  // ---- l reduction: wave w holds partial l for msub=w&1, n-stripe nq ----
  lacc += __shfl_xor(lacc, 32, 64);
  if (h == 0) lred[w][ml] = lacc;
  __syncthreads();
  if (w < 2 && h == 0) {
    float lsum = lred[w][ml] + lred[w + 2][ml] + lred[w + 4][ml] + lred[w + 6][ml];
    lpart[((size_t)nc * Bn + b) * Nn + m0 + w * 32 + ml] = lsum;
  }

  // ---- store unnormalized O^T partials (f16) ----
  _Float16* op0 = Opart + ((size_t)((size_t)nc * Bn + b) * Cc) * Nn + (m0 + ml);
#pragma unroll
  for (int r = 0; r < 16; ++r) {
    int c = c0 + (r & 3) + 8 * (r >> 2) + 4 * h;
    op0[(size_t)c * Nn] = (_Float16)o0[r];
    op0[(size_t)c * Nn + 32] = (_Float16)o1[r];
  }
}

// ---------------------------------------------------------------------------
// Kernel 4: combine chunk partials: out = gamma*(sum O)/(sum l) + input
// ---------------------------------------------------------------------------
__global__ __launch_bounds__(256) void k_fin(const _Float16* __restrict__ Op,
                                             const float* __restrict__ lp,
                                             const float* __restrict__ inp,
                                             const float* __restrict__ gamma,
                                             float* __restrict__ out, int NC) {
  int i4 = (blockIdx.x * 256 + threadIdx.x) * 4;
  int m = i4 & (Nn - 1);
  int bc = i4 >> 12;        // b*256 + c
  int b = bc >> 8;
  float ax = 0.f, ay = 0.f, az = 0.f, aw = 0.f;
  float lx = 0.f, ly = 0.f, lz = 0.f, lw = 0.f;
  for (int nc = 0; nc < NC; ++nc) {
    half4 o = *(const half4*)(Op + ((size_t)nc * Bn * Cc + bc) * Nn + m);
    float4 lv = *(const float4*)(lp + ((size_t)nc * Bn + b) * Nn + m);
    ax += (float)o[0]; ay += (float)o[1]; az += (float)o[2]; aw += (float)o[3];
    lx += lv.x; ly += lv.y; lz += lv.z; lw += lv.w;
  }
  float g = gamma[0];
  float4 xi = *(const float4*)(inp + (size_t)i4);
  float4 r;
  r.x = g * ax / lx + xi.x;
  r.y = g * ay / ly + xi.y;
  r.z = g * az / lz + xi.z;
  r.w = g * aw / lw + xi.w;
  *(float4*)(out + (size_t)i4) = r;
}

// ---------------------------------------------------------------------------
extern "C" void kernel_launch(void* const* d_in, const int* in_sizes, int n_in,
                              void* d_out, int out_size, void* d_ws,
                              size_t ws_size, hipStream_t stream) {
  const float* x = (const float*)d_in[0];
  const float* Wf = (const float*)d_in[1];
  const float* bf = (const float*)d_in[2];
  const float* Wg = (const float*)d_in[3];
  const float* bg = (const float*)d_in[4];
  const float* Wh = (const float*)d_in[5];
  const float* bh = (const float*)d_in[6];
  const float* gamma = (const float*)d_in[7];
  float* out = (float*)d_out;

  char* ws = (char*)d_ws;
  // Layout (bytes):
  //   Q      [0,        1048576)
  //   K4     [1048576,  2097152)
  //   V8     [2097152, 10485760)
  //   M      [10485760, 10551296)
  //   Wfh    [10551296, 10567680)
  //   Wgh    [10567680, 10584064)
  //   Whh    [10584064, 10715136)
  //   lpart  [10715136, 10715136 + NC*65536)
  //   Opart  [.., + NC*8388608)
  _Float16* Q  = (_Float16*)(ws);
  _Float16* K4 = (_Float16*)(ws + 1048576);
  _Float16* V8 = (_Float16*)(ws + 2097152);
  float*    M  = (float*)   (ws + 10485760);
  _Float16* Wfh = (_Float16*)(ws + 10551296);
  _Float16* Wgh = (_Float16*)(ws + 10567680);
  _Float16* Whh = (_Float16*)(ws + 10584064);

  size_t base = 10715136u;
  size_t per_chunk = 65536u + 8388608u;
  int NC = (ws_size >= base + 2u * per_chunk) ? 2 : 1;
  int nspan = Nn / NC;

  float*    lpart = (float*)(ws + base);
  _Float16* Opart = (_Float16*)(ws + base + (size_t)NC * 65536u);

  k_wconv<<<dim3(80), dim3(256), 0, stream>>>(Wf, Wg, Wh, Wfh, Wgh, Whh);
  k_proj<<<dim3(512), dim3(256), 0, stream>>>(x, Wfh, bf, Wgh, bg, Whh, bh, Q, K4, V8);
  k_rowmax<<<dim3(512), dim3(512), 0, stream>>>(Q, K4, M);
  k_attn<<<dim3(NC * 256), dim3(512), 0, stream>>>(Q, K4, V8, M, Opart, lpart, nspan);
  k_fin<<<dim3(4096), dim3(256), 0, stream>>>(Opart, lpart, x, gamma, out, NC);
}

// Round 4
// 163.517 us; speedup vs baseline: 1.3433x; 1.0118x over previous
//
#include <hip/hip_runtime.h>

typedef _Float16 half8 __attribute__((ext_vector_type(8)));
typedef _Float16 half4 __attribute__((ext_vector_type(4)));
typedef unsigned int uintx2 __attribute__((ext_vector_type(2)));
typedef unsigned int uintx4 __attribute__((ext_vector_type(4)));
typedef float floatx16 __attribute__((ext_vector_type(16)));

#define MFMA_F16(A, B, C) __builtin_amdgcn_mfma_f32_32x32x16_f16(A, B, C, 0, 0, 0)

constexpr int Bn = 4;     // batch
constexpr int Cc = 256;   // channels
constexpr int Cq = 32;    // C/8
constexpr int Nn = 4096;  // tokens (64*64)
constexpr float LOG2E = 1.44269504088896340736f;

// Layouts:
//   K4[b][cidx=0..3][n][8] : K fragment chunk cidx=(Cq>>3), dense across lanes
//   V8[b][nb=n>>3][c][8]   : V A-fragment, lane ml -> consecutive 16B chunks

__device__ inline floatx16 zero16() {
  floatx16 z;
#pragma unroll
  for (int i = 0; i < 16; ++i) z[i] = 0.f;
  return z;
}

__device__ inline unsigned int pkrtz(float a, float b) {
  return __builtin_bit_cast(unsigned int, __builtin_amdgcn_cvt_pkrtz(a, b));
}

// ---------------------------------------------------------------------------
// Kernel 0: W fp32 -> f16 (Wf scaled by log2e for exp2-domain softmax).
// ---------------------------------------------------------------------------
__global__ __launch_bounds__(256) void k_wconv(
    const float* __restrict__ Wf, const float* __restrict__ Wg,
    const float* __restrict__ Wh, _Float16* __restrict__ Wfh,
    _Float16* __restrict__ Wgh, _Float16* __restrict__ Whh) {
  int e = (blockIdx.x * 256 + threadIdx.x) * 4;
  const float* src;
  _Float16* dst;
  float sc = 1.f;
  if (e < 8192) { src = Wf + e; dst = Wfh + e; sc = LOG2E; }
  else if (e < 16384) { src = Wg + (e - 8192); dst = Wgh + (e - 8192); }
  else { src = Wh + (e - 16384); dst = Whh + (e - 16384); }
  float4 v = *(const float4*)src;
  half4 o;
  o[0] = (_Float16)(v.x * sc); o[1] = (_Float16)(v.y * sc);
  o[2] = (_Float16)(v.z * sc); o[3] = (_Float16)(v.w * sc);
  *(half4*)dst = o;
}

// ---------------------------------------------------------------------------
// Kernel 1: projections. Stage the 32-token x tile in LDS (transposed,
// coalesced float4 global reads) and build the 16 MFMA B-fragments ONCE per
// wave in registers. Store patterns unchanged from the proven round-9 kernel.
// ---------------------------------------------------------------------------
__global__ __launch_bounds__(256) void k_proj(
    const float* __restrict__ x,
    const _Float16* __restrict__ Wfh, const float* __restrict__ bf,
    const _Float16* __restrict__ Wgh, const float* __restrict__ bg,
    const _Float16* __restrict__ Whh, const float* __restrict__ bh,
    _Float16* __restrict__ Q, _Float16* __restrict__ K4,
    _Float16* __restrict__ V8) {
  __shared__ float xs[32][260];  // pad 260: 16B-aligned rows, ~4-way on read
  int tid = threadIdx.x;
  int w = tid >> 6, lane = tid & 63;
  int ml = lane & 31, h = lane >> 5;
  int b = blockIdx.x >> 7, nt = blockIdx.x & 127;
  int n0 = nt * 32;

  // ---- stage x[b][0..255][n0..n0+31] transposed into xs[n_local][c] ----
  {
    int c = tid >> 3;          // 0..31
    int nl = (tid & 7) * 4;    // 4 consecutive tokens per thread
    const float* xp = x + (size_t)b * Cc * Nn + n0 + nl;
#pragma unroll
    for (int pass = 0; pass < 8; ++pass) {
      int cc = c + pass * 32;
      float4 v = *(const float4*)(xp + (size_t)cc * Nn);
      xs[nl + 0][cc] = v.x;
      xs[nl + 1][cc] = v.y;
      xs[nl + 2][cc] = v.z;
      xs[nl + 3][cc] = v.w;
    }
  }
  __syncthreads();

  // ---- build all 16 B-fragments once (lane ml = token n0+ml) ----
  half8 bfr[16];
#pragma unroll
  for (int kc = 0; kc < 16; ++kc) {
    const float* xp = &xs[ml][kc * 16 + h * 8];
    half8 f;
#pragma unroll
    for (int j = 0; j < 8; ++j) f[j] = (_Float16)xp[j];  // RTE
    bfr[kc] = f;
  }

  for (int t = w; t < 10; t += 4) {
    const _Float16* W;
    const float* bias;
    float bscale = 1.f;
    int o0 = 0;
    if (t == 0) { W = Wfh; bias = bf; bscale = LOG2E; }
    else if (t == 1) { W = Wgh; bias = bg; }
    else { W = Whh + (size_t)(t - 2) * 32 * Cc; bias = bh + (t - 2) * 32; o0 = (t - 2) * 32; }

    floatx16 acc = zero16();
    const _Float16* wp = W + (size_t)ml * Cc + h * 8;
#pragma unroll
    for (int kc = 0; kc < 16; ++kc) {
      half8 a = *(const half8*)(wp + kc * 16);
      acc = MFMA_F16(a, bfr[kc], acc);
    }

    if (t == 0) {
      // Q token-major Q[b][n][o]
      _Float16* op = Q + ((size_t)b * Nn + n0 + ml) * Cq;
#pragma unroll
      for (int qd = 0; qd < 4; ++qd) {
        float4 bq = *(const float4*)(bias + 8 * qd + 4 * h);
        const float* bqp = (const float*)&bq;
#pragma unroll
        for (int i = 0; i < 4; ++i) {
          int crow = i + 8 * qd + 4 * h;
          op[crow] = (_Float16)(acc[4 * qd + i] + bqp[i] * bscale);
        }
      }
    } else if (t == 1) {
      // K4[b][crow>>3][n][crow&7]
#pragma unroll
      for (int qd = 0; qd < 4; ++qd) {
        float4 bq = *(const float4*)(bias + 8 * qd + 4 * h);
        const float* bqp = (const float*)&bq;
#pragma unroll
        for (int i = 0; i < 4; ++i) {
          int crow = i + 8 * qd + 4 * h;
          K4[(((size_t)b * 4 + (crow >> 3)) * Nn + n0 + ml) * 8 + (crow & 7)] =
              (_Float16)(acc[4 * qd + i] + bqp[i]);
        }
      }
    } else {
      // V8[b][(n0+ml)>>3][c][ml&7]
      size_t nb = (size_t)((n0 + ml) >> 3);
      _Float16* op = V8 + (((size_t)b * 512 + nb) * 256) * 8 + (ml & 7);
#pragma unroll
      for (int qd = 0; qd < 4; ++qd) {
        float4 bq = *(const float4*)(bias + 8 * qd + 4 * h);
        const float* bqp = (const float*)&bq;
#pragma unroll
        for (int i = 0; i < 4; ++i) {
          int crow = i + 8 * qd + 4 * h;
          op[(size_t)(o0 + crow) * 8] = (_Float16)(acc[4 * qd + i] + bqp[i]);
        }
      }
    }
  }
}

// ---------------------------------------------------------------------------
// Kernel 2: pass-1 row max (log2-domain), K4 coalesced loads.
// MFMA bitwise identical to k_attn's S -> exp2(s-M) <= 1 exactly.
// ---------------------------------------------------------------------------
__global__ __launch_bounds__(512) void k_rowmax(const _Float16* __restrict__ Q,
                                                const _Float16* __restrict__ K4,
                                                float* __restrict__ M) {
  __shared__ float red[8][32];
  int tid = threadIdx.x, w = tid >> 6, lane = tid & 63;
  int ml = lane & 31, h = lane >> 5;
  int b = blockIdx.x >> 7, mt = blockIdx.x & 127;
  int m0 = mt * 32;
  const _Float16* qp = Q + ((size_t)b * Nn + m0 + ml) * Cq + h * 8;
  half8 qb0 = *(const half8*)(qp);
  half8 qb1 = *(const half8*)(qp + 16);
  const _Float16* kp0 = K4 + (((size_t)b * 4 + h) * Nn + w * 512 + ml) * 8;
  const _Float16* kp1 = K4 + (((size_t)b * 4 + 2 + h) * Nn + w * 512 + ml) * 8;
  float mx = -3.0e38f;
  for (int t = 0; t < 16; ++t) {
    floatx16 s = zero16();
    half8 k0 = *(const half8*)(kp0 + (size_t)t * 32 * 8);
    half8 k1 = *(const half8*)(kp1 + (size_t)t * 32 * 8);
    s = MFMA_F16(k0, qb0, s);
    s = MFMA_F16(k1, qb1, s);
#pragma unroll
    for (int i = 0; i < 16; ++i) mx = fmaxf(mx, s[i]);
  }
  mx = fmaxf(mx, __shfl_xor(mx, 32, 64));
  if (h == 0) red[w][ml] = mx;
  __syncthreads();
  if (tid < 32) {
    float m2 = red[0][tid];
#pragma unroll
    for (int i = 1; i < 8; ++i) m2 = fmaxf(m2, red[i][tid]);
    M[(size_t)b * Nn + m0 + tid] = m2;
  }
}

// ---------------------------------------------------------------------------
// O-tree helpers: per-wave O tile (256c x 32m f32) <-> LDS region (32KB).
// Layout: float2 index ((cb*8+rp)*2 + h)*32 + ml  (2-way bank = free).
// ---------------------------------------------------------------------------
__device__ inline void otree_write(float2* dst, const floatx16* o) {
#pragma unroll
  for (int cb = 0; cb < 8; ++cb)
#pragma unroll
    for (int rp = 0; rp < 8; ++rp)
      dst[(cb * 8 + rp) * 64] = make_float2(o[cb][2 * rp], o[cb][2 * rp + 1]);
}

__device__ inline void otree_add(const float2* src, floatx16* o) {
#pragma unroll
  for (int cb = 0; cb < 8; ++cb)
#pragma unroll
    for (int rp = 0; rp < 8; ++rp) {
      float2 v = src[(cb * 8 + rp) * 64];
      o[cb][2 * rp] += v.x;
      o[cb][2 * rp + 1] += v.y;
    }
}

// ---------------------------------------------------------------------------
// Kernel 3: pass-2 attention, round-4 rewrite.
// Block = 32 m-rows, 8 waves = 8 n-slices. Per iter each wave: S (2 MFMA over
// its 32 n) -> exp2 -> cvt_pkrtz + permlane32_swap assembles PV B-fragments
// IN REGISTERS (no LDS, no barrier in the main loop) -> 16 PV MFMA over all
// 256 channels (8 floatx16 accumulators).
// S MFMA operand sequence bitwise identical to k_rowmax => exp2(s-M) <= 1.
// End: LDS tree-reduce the 8 per-wave O partials (f32), fused epilogue
// (gamma * O/l + x) writes final output. k_fin eliminated.
// ---------------------------------------------------------------------------
__global__ __launch_bounds__(512, 2) void k_attn(
    const _Float16* __restrict__ Q, const _Float16* __restrict__ K4,
    const _Float16* __restrict__ V8, const float* __restrict__ M,
    const float* __restrict__ xin, const float* __restrict__ gamma,
    float* __restrict__ out) {
  __shared__ float Ored[4 * 8192];   // 4 tree regions x 32KB
  __shared__ float lred[8][32];
  int tid = threadIdx.x, w = tid >> 6, lane = tid & 63;
  int ml = lane & 31, h = lane >> 5;
  int bx = blockIdx.x;
  int mt = bx & 127, b = bx >> 7;
  int m0 = mt * 32;

  const _Float16* qp = Q + ((size_t)b * Nn + m0 + ml) * Cq + h * 8;
  half8 qb0 = *(const half8*)(qp);
  half8 qb1 = *(const half8*)(qp + 16);
  float Mv = M[(size_t)b * Nn + m0 + ml];
  float g = gamma[0];
  float lacc = 0.f;

  // K fragments: n = it*256 + w*32 + ml (coalesced across ml)
  const _Float16* k4b0 = K4 + (((size_t)b * 4 + h) * Nn + w * 32 + ml) * 8;
  const _Float16* k4b1 = K4 + (((size_t)b * 4 + 2 + h) * Nn + w * 32 + ml) * 8;
  // V8: nb = it*32 + w*4 + kc*2 + h ; element ((b*512+nb)*256 + c)*8
  const _Float16* v8b = V8 + (((size_t)b * 512 + w * 4 + h) * 256 + ml) * 8;

  floatx16 o[8];
#pragma unroll
  for (int i = 0; i < 8; ++i) o[i] = zero16();

  half8 k0 = *(const half8*)(k4b0);
  half8 k1 = *(const half8*)(k4b1);

  for (int it = 0; it < 16; ++it) {
    // ---- S: 32m x 32n for this wave's n-slice ----
    floatx16 s = zero16();
    s = MFMA_F16(k0, qb0, s);
    s = MFMA_F16(k1, qb1, s);
    // prefetch next iter's K (it=15 overruns into V8 region: benign)
    k0 = *(const half8*)(k4b0 + (size_t)(it + 1) * 2048);
    k1 = *(const half8*)(k4b1 + (size_t)(it + 1) * 2048);
    // ---- softmax numerator, in-register pack + half-swap ----
    float p[16];
#pragma unroll
    for (int i = 0; i < 16; ++i) p[i] = __builtin_amdgcn_exp2f(s[i] - Mv);
#pragma unroll
    for (int i = 0; i < 16; ++i) lacc += p[i];
    unsigned int c0 = pkrtz(p[0], p[1]),  c1 = pkrtz(p[2], p[3]);
    unsigned int c2 = pkrtz(p[4], p[5]),  c3 = pkrtz(p[6], p[7]);
    unsigned int c4 = pkrtz(p[8], p[9]),  c5 = pkrtz(p[10], p[11]);
    unsigned int c6 = pkrtz(p[12], p[13]), c7 = pkrtz(p[14], p[15]);
    // newD = [D(0:31) | S(0:31)], newS = [D(32:63) | S(32:63)]
    uintx2 t02 = __builtin_amdgcn_permlane32_swap(c0, c2, false, false);
    uintx2 t13 = __builtin_amdgcn_permlane32_swap(c1, c3, false, false);
    uintx2 t46 = __builtin_amdgcn_permlane32_swap(c4, c6, false, false);
    uintx2 t57 = __builtin_amdgcn_permlane32_swap(c5, c7, false, false);
    uintx4 f0v = {t02.x, t13.x, t02.y, t13.y};   // n-offsets  0..15 (k = h*8+j)
    uintx4 f1v = {t46.x, t57.x, t46.y, t57.y};   // n-offsets 16..31
    half8 pf0 = __builtin_bit_cast(half8, f0v);
    half8 pf1 = __builtin_bit_cast(half8, f1v);
    // ---- PV: all 256 channels for this n-slice ----
    const _Float16* vp = v8b + (size_t)it * 65536;  // 32 nb * 256c * 8
#pragma unroll
    for (int cb = 0; cb < 8; ++cb) {
      half8 vf0 = *(const half8*)(vp + cb * 256);
      o[cb] = MFMA_F16(vf0, pf0, o[cb]);
    }
#pragma unroll
    for (int cb = 0; cb < 8; ++cb) {
      half8 vf1 = *(const half8*)(vp + 4096 + cb * 256);
      o[cb] = MFMA_F16(vf1, pf1, o[cb]);
    }
  }

  // ---- l partials ----
  lacc += __shfl_xor(lacc, 32, 64);
  if (h == 0) lred[w][ml] = lacc;

  // ---- O tree reduction across 8 n-slice waves ----
  float2* Ored2 = (float2*)Ored;
  int lofs = h * 32 + ml;
  if (w >= 4) otree_write(Ored2 + (w - 4) * 4096 + lofs, o);
  __syncthreads();
  if (w < 4) otree_add(Ored2 + w * 4096 + lofs, o);
  __syncthreads();
  if (w == 2 || w == 3) otree_write(Ored2 + (w - 2) * 4096 + lofs, o);
  __syncthreads();
  if (w < 2) otree_add(Ored2 + w * 4096 + lofs, o);
  __syncthreads();
  if (w == 1) otree_write(Ored2 + lofs, o);
  __syncthreads();
  if (w == 0) { otree_add(Ored2 + lofs, o); otree_write(Ored2 + lofs, o); }
  __syncthreads();

  // ---- fused epilogue: wave w handles channel block cb = w ----
  float lv = 0.f;
#pragma unroll
  for (int i = 0; i < 8; ++i) lv += lred[i][ml];
  float scale = g / lv;
  const float2* src = Ored2 + lofs;
  size_t obase = ((size_t)b * 256 + w * 32) * (size_t)Nn + m0 + ml;
#pragma unroll
  for (int rp = 0; rp < 8; ++rp) {
    float2 v = src[(w * 8 + rp) * 64];
    int r = 2 * rp;
    int cA = (r & 3) + 8 * (r >> 2) + 4 * h;
    size_t oa = obase + (size_t)cA * Nn;
    out[oa] = scale * v.x + xin[oa];
    out[oa + Nn] = scale * v.y + xin[oa + Nn];
  }
}

// ---------------------------------------------------------------------------
extern "C" void kernel_launch(void* const* d_in, const int* in_sizes, int n_in,
                              void* d_out, int out_size, void* d_ws,
                              size_t ws_size, hipStream_t stream) {
  const float* x = (const float*)d_in[0];
  const float* Wf = (const float*)d_in[1];
  const float* bf = (const float*)d_in[2];
  const float* Wg = (const float*)d_in[3];
  const float* bg = (const float*)d_in[4];
  const float* Wh = (const float*)d_in[5];
  const float* bh = (const float*)d_in[6];
  const float* gamma = (const float*)d_in[7];
  float* out = (float*)d_out;

  char* ws = (char*)d_ws;
  // Layout (bytes):
  //   Q      [0,        1048576)
  //   K4     [1048576,  2097152)
  //   V8     [2097152, 10485760)
  //   M      [10485760, 10551296)
  //   Wfh    [10551296, 10567680)
  //   Wgh    [10567680, 10584064)
  //   Whh    [10584064, 10715136)
  _Float16* Q  = (_Float16*)(ws);
  _Float16* K4 = (_Float16*)(ws + 1048576);
  _Float16* V8 = (_Float16*)(ws + 2097152);
  float*    M  = (float*)   (ws + 10485760);
  _Float16* Wfh = (_Float16*)(ws + 10551296);
  _Float16* Wgh = (_Float16*)(ws + 10567680);
  _Float16* Whh = (_Float16*)(ws + 10584064);

  k_wconv<<<dim3(80), dim3(256), 0, stream>>>(Wf, Wg, Wh, Wfh, Wgh, Whh);
  k_proj<<<dim3(512), dim3(256), 0, stream>>>(x, Wfh, bf, Wgh, bg, Whh, bh, Q, K4, V8);
  k_rowmax<<<dim3(512), dim3(512), 0, stream>>>(Q, K4, M);
  k_attn<<<dim3(512), dim3(512), 0, stream>>>(Q, K4, V8, M, x, gamma, out);
}